// Round 1
// baseline (102.791 us; speedup 1.0000x reference)
//
#include <hip/hip_runtime.h>

#define NDIM 64
#define NRANK 8
#define NK 16
#define CSTRIDE 641               // 1 + 64 + 512 + 64
#define ROWSTRIDE (CSTRIDE * NK)  // 10256

// ---- cross-lane helpers -------------------------------------------------

template <int CTRL>
__device__ __forceinline__ float dpp_mov(float x) {
  int t = __builtin_amdgcn_update_dpp(0, __builtin_bit_cast(int, x), CTRL,
                                      0xF, 0xF, true);
  return __builtin_bit_cast(float, t);
}

// sum across the 4 lanes of a quad (lane bits 0..1); result in all 4 lanes
__device__ __forceinline__ void quad_reduce(float& x) {
  x += dpp_mov<0xB1>(x);  // quad_perm [1,0,3,2]  (xor 1)
  x += dpp_mov<0x4E>(x);  // quad_perm [2,3,0,1]  (xor 2)
}

// ---- kernel -------------------------------------------------------------
// One wave per batch row b. lane = k*4 + dg  (k = component, dg = dim group).
// Lane handles dims d = dg + 4*i, i = 0..15, of component k.

__global__ __launch_bounds__(256) void gmm_nll_kernel(
    const float* __restrict__ pred, const float* __restrict__ label,
    float* __restrict__ out, int nb) {
  const int lane = threadIdx.x & 63;
  const int b = (int)((blockIdx.x * blockDim.x + threadIdx.x) >> 6);
  if (b >= nb) return;
  const int k = lane >> 2;
  const int dg = lane & 3;

  const float* row = pred + (size_t)b * ROWSTRIDE;
  const float* comp = row + k * CSTRIDE;
  const float* Wb = comp + 1 + NDIM + dg * NRANK;              // W[dg][0..7]
  const float* mub = comp + 1 + dg;                            // mu[dg]
  const float* ldb = comp + 1 + NDIM + NDIM * NRANK + dg;      // log d[dg]
  const float* lbb = label + (size_t)b * NDIM + dg;

  float capL[NRANK][NRANK];  // lower triangle (s <= r) used
  float bv[NRANK];
#pragma unroll
  for (int r = 0; r < NRANK; ++r) {
    bv[r] = 0.f;
#pragma unroll
    for (int s = 0; s <= r; ++s) capL[r][s] = 0.f;
  }
  float mahal1 = 0.f, ldsum = 0.f;

#pragma unroll
  for (int i = 0; i < NDIM / 4; ++i) {
    float4 w0, w1;
    __builtin_memcpy(&w0, Wb + 32 * i, 16);       // only 4B-aligned in general
    __builtin_memcpy(&w1, Wb + 32 * i + 4, 16);
    float mu = mub[4 * i];
    float ld = ldb[4 * i];
    float lb = lbb[4 * i];

    float sd = __expf(-0.5f * ld);  // sqrt(1/d)
    float diff = lb - mu;
    float u = diff * sd;
    mahal1 = fmaf(u, u, mahal1);    // sum diff^2 / d
    ldsum += ld;                    // sum log d

    float v[NRANK];
    v[0] = w0.x * sd; v[1] = w0.y * sd; v[2] = w0.z * sd; v[3] = w0.w * sd;
    v[4] = w1.x * sd; v[5] = w1.y * sd; v[6] = w1.z * sd; v[7] = w1.w * sd;
#pragma unroll
    for (int r = 0; r < NRANK; ++r) {
      bv[r] = fmaf(v[r], u, bv[r]);
#pragma unroll
      for (int s = 0; s <= r; ++s)
        capL[r][s] = fmaf(v[r], v[s], capL[r][s]);
    }
  }

  // reduce partial sums across the 4 dg lanes (quad) — all lanes get totals
  quad_reduce(mahal1);
  quad_reduce(ldsum);
#pragma unroll
  for (int r = 0; r < NRANK; ++r) {
    quad_reduce(bv[r]);
#pragma unroll
    for (int s = 0; s <= r; ++s) quad_reduce(capL[r][s]);
  }

  // cap = I + W^T D^-1 W
#pragma unroll
  for (int r = 0; r < NRANK; ++r) capL[r][r] += 1.0f;

  // in-place Cholesky (lower), fully unrolled
  float invd[NRANK];
  float logdetL = 0.f;
#pragma unroll
  for (int j = 0; j < NRANK; ++j) {
    float s = capL[j][j];
#pragma unroll
    for (int p = 0; p < j; ++p) s = fmaf(-capL[j][p], capL[j][p], s);
    float ljj = sqrtf(s);
    float inv = 1.0f / ljj;
    invd[j] = inv;
    logdetL += __logf(ljj);
#pragma unroll
    for (int i2 = j + 1; i2 < NRANK; ++i2) {
      float t = capL[i2][j];
#pragma unroll
      for (int p = 0; p < j; ++p) t = fmaf(-capL[i2][p], capL[j][p], t);
      capL[i2][j] = t * inv;
    }
  }

  // forward solve L y = b, accumulate |y|^2
  float y[NRANK];
  float ysq = 0.f;
#pragma unroll
  for (int i2 = 0; i2 < NRANK; ++i2) {
    float t = bv[i2];
#pragma unroll
    for (int j = 0; j < i2; ++j) t = fmaf(-capL[i2][j], y[j], t);
    y[i2] = t * invd[i2];
    ysq = fmaf(y[i2], y[i2], ysq);
  }

  float mahal = mahal1 - ysq;
  float logdet = 2.0f * logdetL + ldsum;
  const float c_dim_log2pi = 117.62413225019810f;  // 64 * log(2*pi)
  float comp_lp = -0.5f * (c_dim_log2pi + logdet + mahal);

  float pi = comp[0];

  // logsumexp over k (lane bits 2..5): lse(pis) and lse(pis + comp_lp)
  float m1 = pi;
  m1 = fmaxf(m1, __shfl_xor(m1, 4));
  m1 = fmaxf(m1, __shfl_xor(m1, 8));
  m1 = fmaxf(m1, __shfl_xor(m1, 16));
  m1 = fmaxf(m1, __shfl_xor(m1, 32));
  float e1 = __expf(pi - m1);
  e1 += __shfl_xor(e1, 4);
  e1 += __shfl_xor(e1, 8);
  e1 += __shfl_xor(e1, 16);
  e1 += __shfl_xor(e1, 32);
  float lse_pi = m1 + __logf(e1);

  float t2 = pi + comp_lp;
  float m2 = t2;
  m2 = fmaxf(m2, __shfl_xor(m2, 4));
  m2 = fmaxf(m2, __shfl_xor(m2, 8));
  m2 = fmaxf(m2, __shfl_xor(m2, 16));
  m2 = fmaxf(m2, __shfl_xor(m2, 32));
  float e2 = __expf(t2 - m2);
  e2 += __shfl_xor(e2, 4);
  e2 += __shfl_xor(e2, 8);
  e2 += __shfl_xor(e2, 16);
  e2 += __shfl_xor(e2, 32);
  float lse_t = m2 + __logf(e2);

  // nll = -(lse(pi + comp_lp) - lse(pi))
  if (lane == 0) out[b] = lse_pi - lse_t;
}

extern "C" void kernel_launch(void* const* d_in, const int* in_sizes, int n_in,
                              void* d_out, int out_size, void* d_ws,
                              size_t ws_size, hipStream_t stream) {
  const float* pred = (const float*)d_in[0];
  const float* label = (const float*)d_in[1];
  float* out = (float*)d_out;
  const int nb = out_size;  // 8192
  const int blocks = (nb + 3) / 4;  // 4 waves (4 rows) per 256-thread block
  gmm_nll_kernel<<<dim3(blocks), dim3(256), 0, stream>>>(pred, label, out, nb);
}